// Round 2
// baseline (116.535 us; speedup 1.0000x reference)
//
#include <hip/hip_runtime.h>

// out[b,m,p] (B=512, OUT=400):
//   = x[b,m,p]            for m<256 && p<256   (eye is the identity embedding)
//   = 1.0f                for m==p >= 256      (add = diag(0*256, 1*144))
//   = 0.0f                otherwise
// Pure streaming: 134MB read + 328MB write. No add/eye buffer reads needed.

constexpr unsigned B   = 512;
constexpr unsigned IN  = 256;
constexpr unsigned OUT = 400;
constexpr unsigned ROW4  = OUT / 4;          // 100 float4 per out row
constexpr unsigned BROW4 = OUT * ROW4;       // 40000 float4 per batch matrix

// ---------------- K1: copy x into the top-left 256x256 block ----------------
// i in [0, 512*256*64): b = i>>14, m = (i>>6)&255, p4 = i&63. Shifts only.
__global__ __launch_bounds__(256) void k_copy_x(
    const float4* __restrict__ x4, float4* __restrict__ out4)
{
    unsigned i = blockIdx.x * 256u + threadIdx.x;   // one float4 per thread
    unsigned b  = i >> 14;
    unsigned m  = (i >> 6) & 255u;
    unsigned p4 = i & 63u;
    out4[b * BROW4 + m * ROW4 + p4] = x4[i];
}

// ---------------- K2: fill the complement (zeros + diagonal ones) -----------
// part A: right pad of rows m<256:   512*256 rows x 36 f4  (all zero)
// part B: rows m in [256,400):       512*144 rows x 100 f4 (zero + one diag elem)
constexpr unsigned PAD_F4  = B * IN * 36u;           // 4,718,592
constexpr unsigned BOT_F4  = B * (OUT - IN) * ROW4;  // 7,372,800

__global__ __launch_bounds__(256) void k_fill_rest(float4* __restrict__ out4)
{
    unsigned i = blockIdx.x * 256u + threadIdx.x;
    if (i < PAD_F4) {
        // right pad: row = b*256+m, p4 = 64 + i%36
        unsigned row = i / 36u;                // magic-mul
        unsigned p4  = 64u + (i - row * 36u);
        unsigned b   = row >> 8;
        unsigned m   = row & 255u;
        out4[b * BROW4 + m * ROW4 + p4] = float4{0.f, 0.f, 0.f, 0.f};
    } else {
        unsigned j   = i - PAD_F4;             // [0, 7,372,800)
        unsigned row = j / 100u;               // magic-mul; row in [0, 512*144)
        unsigned p4  = j - row * 100u;
        unsigned b   = row / 144u;             // magic-mul
        unsigned mm  = row - b * 144u;         // m = 256 + mm
        float4 v{0.f, 0.f, 0.f, 0.f};
        unsigned m = IN + mm;
        if (p4 == (m >> 2)) {                  // f4 containing the diagonal
            ((float*)&v)[m & 3u] = 1.0f;
        }
        out4[b * BROW4 + m * ROW4 + p4] = v;
    }
}

extern "C" void kernel_launch(void* const* d_in, const int* in_sizes, int n_in,
                              void* d_out, int out_size, void* d_ws, size_t ws_size,
                              hipStream_t stream)
{
    const float4* x4 = (const float4*)d_in[0];  // [B, IN, IN], contiguous
    float4* out4 = (float4*)d_out;              // [B, OUT, OUT]

    constexpr unsigned COPY_F4 = B * IN * (IN / 4);     // 8,388,608
    constexpr unsigned FILL_F4 = PAD_F4 + BOT_F4;       // 12,091,392

    k_copy_x  <<<COPY_F4 / 256, 256, 0, stream>>>(x4, out4);
    k_fill_rest<<<(FILL_F4 + 255) / 256, 256, 0, stream>>>(out4);
}

// Round 4
// 87.182 us; speedup vs baseline: 1.3367x; 1.3367x over previous
//
#include <hip/hip_runtime.h>

// out[b,m,p] (B=512, OUT=400):
//   = x[b,m,p]   for m<256 && p<256   (eye = identity embedding)
//   = 1.0f       for m==p >= 256      (add = diag(0*256, 1*144))
//   = 0.0f       otherwise
// Single pass, contiguous output writes, no eye/add reads, non-temporal.
// Traffic: 134.2MB read (x) + 327.7MB write (out).

typedef float f32x4 __attribute__((ext_vector_type(4)));

constexpr unsigned B   = 512;
constexpr unsigned IN  = 256;
constexpr unsigned OUT = 400;
constexpr unsigned ROW4 = OUT / 4;                 // 100 float4 per out row
constexpr unsigned TOTAL_F4 = B * OUT * ROW4;      // 20,480,000

__global__ __launch_bounds__(256) void spd_onepass(
    const f32x4* __restrict__ x4, f32x4* __restrict__ out4)
{
    const unsigned stride = gridDim.x * 256u;
    for (unsigned i = blockIdx.x * 256u + threadIdx.x; i < TOTAL_F4; i += stride) {
        unsigned bm = i / 100u;              // compiler -> magic mulhi
        unsigned p4 = i - bm * 100u;
        unsigned b  = bm / 400u;             // magic mulhi
        unsigned m  = bm - b * 400u;

        f32x4 v;
        if (m < IN && p4 < (IN / 4)) {
            // x[b][m][p4] : b*16384 + m*64 + p4, non-temporal (read once)
            v = __builtin_nontemporal_load(&x4[(b << 14) + (m << 6) + p4]);
        } else {
            v = (f32x4){0.f, 0.f, 0.f, 0.f};
            if (m >= IN && p4 == (m >> 2)) {
                v[m & 3u] = 1.0f;            // diagonal one from `add`
            }
        }
        // out is write-once, never re-read: bypass L2 allocate
        __builtin_nontemporal_store(v, &out4[i]);
    }
}

extern "C" void kernel_launch(void* const* d_in, const int* in_sizes, int n_in,
                              void* d_out, int out_size, void* d_ws, size_t ws_size,
                              hipStream_t stream)
{
    const f32x4* x4 = (const f32x4*)d_in[0];  // [B, IN, IN]
    f32x4* out4 = (f32x4*)d_out;              // [B, OUT, OUT]

    spd_onepass<<<2048, 256, 0, stream>>>(x4, out4);
}